// Round 7
// baseline (1374.075 us; speedup 1.0000x reference)
//
#include <hip/hip_runtime.h>

// Problem constants (B=8, S=2048, D=512, H=4, HD=128, K=4096)
#define N_TOK 16384          // B*S
#define HEADS 4
#define HD_   128
#define KC    4096
#define XELEMS 8388608       // N_TOK * HEADS * HD_
#define DIFFOFF 8388608
#define IDXOFF  8388609

// argmin kernel geometry
#define MT 128               // tokens per block
#define NC 64                // codes per chunk
#define NCHUNK (KC / NC)     // 64

// Scratch layout inside d_out's quantize region (overwritten by gather at end):
#define EE32_OFF 0           // 16384 floats
#define EE64_OFF 16384       // 16384 doubles (byte off 65536, 8-aligned)
#define CNT_OFF  49152       // 1 int
#define CAND_OFF 49153       // up to 65536 ints
#define CAND_CAP 65536

#define MARGIN 2.0f          // fp32 pass error ~0.02 -> 100x slack

typedef const __attribute__((address_space(1))) void ga_void;
typedef __attribute__((address_space(3))) void la_void;

// ---------------------------------------------------------------------------
// Kernel 1: ee[h][k] = sum_d embed[h][d][k]^2 in fp64; store fp32 + fp64.
// ---------------------------------------------------------------------------
__global__ __launch_bounds__(256) void vq_ee_kernel(const float* __restrict__ e,
                                                    float* __restrict__ ee32,
                                                    double* __restrict__ ee64) {
  int h = blockIdx.y;
  int k = blockIdx.x * 256 + threadIdx.x;
  const float* eh = e + (size_t)h * HD_ * KC;
  double s = 0.0;
#pragma unroll 8
  for (int d = 0; d < HD_; ++d) {
    double v = (double)eh[(size_t)d * KC + k];
    s = fma(v, v, s);
  }
  ee32[h * KC + k] = (float)s;
  ee64[h * KC + k] = s;
}

// ---------------------------------------------------------------------------
// Kernel 2: fp32 screening argmin, GEMM-structured.
// 512 threads, M-tile=128 tokens (one head), K streamed in 64-code chunks.
// xs[d][token] staged once (64KB); es double-buffered (2x32KB) via async
// global_load_lds (width 16) prefetched one chunk ahead. 4x4 micro-tile.
// val = ee - 2*dot (||x||^2 row-uniform: dropped; argmin & margin unchanged).
// Rows whose (second - best) < MARGIN are flagged for fp64 rescue.
// ---------------------------------------------------------------------------
__global__ __launch_bounds__(512, 2) void vq_argmin_kernel(
    const float* __restrict__ x, const float* __restrict__ e,
    const float* __restrict__ ee, float* __restrict__ idx_out,
    int* __restrict__ cnt, int* __restrict__ cand) {
  __shared__ float xs[HD_][MT];        // 64KB, [d][token]
  __shared__ float es[2][HD_][NC];     // 64KB, [buf][d][code]

  const int t    = threadIdx.x;
  const int lane = t & 63;
  const int w    = t >> 6;             // wave 0..7
  const int h    = blockIdx.y;
  const int n0   = blockIdx.x * MT;
  const int tc   = t & 15;             // code group (4 codes)
  const int tr   = t >> 4;             // row group (4 rows), 0..31
  const float* eh = e + (size_t)h * HD_ * KC;

  // ---- stage x tile transposed: xs[d][r] (once; scattered ds_write, 1-time)
  {
    const int r = t >> 2, c = t & 3;   // token r, 32-d segment c
    const float* xp = x + ((size_t)(n0 + r) * HEADS + h) * HD_ + c * 32;
#pragma unroll
    for (int i = 0; i < 8; ++i) {
      float4 v = *reinterpret_cast<const float4*>(xp + i * 4);
      int d = c * 32 + i * 4;
      xs[d + 0][r] = v.x; xs[d + 1][r] = v.y;
      xs[d + 2][r] = v.z; xs[d + 3][r] = v.w;
    }
  }

  // ---- async stage of a 64-code chunk: es[buf][d][c], linear LDS order.
  // segment s (1KB) = wave-uniform; lane slot = s*64+lane -> d=slot/16, c4=slot%16
  auto stage = [&](int k0, int buf) {
    float* dst_base = &es[buf][0][0];
#pragma unroll
    for (int j = 0; j < 4; ++j) {
      int s    = w * 4 + j;
      int slot = s * 64 + lane;
      int d    = slot >> 4, c4 = slot & 15;
      const float* src = eh + (size_t)d * KC + k0 + c4 * 4;
      __builtin_amdgcn_global_load_lds((ga_void*)src,
                                       (la_void*)(dst_base + s * 256),
                                       16, 0, 0);
    }
  };

  stage(0, 0);
  __syncthreads();  // drains vmcnt; xs + chunk0 ready

  float b1[4], b2[4];
  int   i1[4];
#pragma unroll
  for (int i = 0; i < 4; ++i) { b1[i] = __builtin_inff(); b2[i] = __builtin_inff(); i1[i] = 0; }

  for (int c = 0; c < NCHUNK; ++c) {
    const int buf = c & 1;
    if (c + 1 < NCHUNK) stage((c + 1) * NC, buf ^ 1);  // prefetch ahead

    float acc[4][4];
#pragma unroll
    for (int i = 0; i < 4; ++i)
#pragma unroll
      for (int j = 0; j < 4; ++j) acc[i][j] = 0.f;

#pragma unroll 4
    for (int d = 0; d < HD_; ++d) {
      float4 xv = *reinterpret_cast<const float4*>(&xs[d][tr * 4]);
      float4 ev = *reinterpret_cast<const float4*>(&es[buf][d][tc * 4]);
      float xa[4] = {xv.x, xv.y, xv.z, xv.w};
      float ea[4] = {ev.x, ev.y, ev.z, ev.w};
#pragma unroll
      for (int i = 0; i < 4; ++i)
#pragma unroll
        for (int j = 0; j < 4; ++j) acc[i][j] = fmaf(xa[i], ea[j], acc[i][j]);
    }

    float4 eev = *reinterpret_cast<const float4*>(ee + h * KC + c * NC + tc * 4);
    float ea[4] = {eev.x, eev.y, eev.z, eev.w};
    const int code0 = c * NC + tc * 4;
#pragma unroll
    for (int j = 0; j < 4; ++j) {
#pragma unroll
      for (int i = 0; i < 4; ++i) {
        float val = fmaf(-2.0f, acc[i][j], ea[j]);
        if (val < b1[i]) { b2[i] = b1[i]; b1[i] = val; i1[i] = code0 + j; }
        else if (val < b2[i]) { b2[i] = val; }
      }
    }
    __syncthreads();  // protects es[buf] reuse + drains next-chunk prefetch
  }

  // ---- cross-thread (tc) reduction per row: best + second-best ----
  // reduction arrays alias es (all reads done; last barrier passed)
  float* redV  = &es[0][0][0];                 // 128*16 floats
  float* redV2 = redV + MT * 16;               // 128*16 floats
  int*   redI  = (int*)(redV2 + MT * 16);      // 128*16 ints
#pragma unroll
  for (int i = 0; i < 4; ++i) {
    redV [(tr * 4 + i) * 16 + tc] = b1[i];
    redV2[(tr * 4 + i) * 16 + tc] = b2[i];
    redI [(tr * 4 + i) * 16 + tc] = i1[i];
  }
  __syncthreads();
  if (t < MT) {
    float bv1 = redV[t * 16], bv2 = redV2[t * 16];
    int   bi1 = redI[t * 16];
#pragma unroll
    for (int cc = 1; cc < 16; ++cc) {
      float v1 = redV[t * 16 + cc], v2 = redV2[t * 16 + cc];
      int  ci = redI[t * 16 + cc];
      if (v1 < bv1 || (v1 == bv1 && ci < bi1)) {
        bv2 = fminf(bv1, v2);
        bv1 = v1; bi1 = ci;
      } else {
        bv2 = fminf(bv2, v1);
      }
    }
    idx_out[(size_t)(n0 + t) * HEADS + h] = (float)bi1;
    if (bv2 - bv1 < MARGIN) {  // near-tie: needs fp64 rescue
      int slot = atomicAdd(cnt, 1);
      if (slot < CAND_CAP) cand[slot] = (n0 + t) * HEADS + h;
    }
  }
}

// ---------------------------------------------------------------------------
// Kernel 2b: fp64 exact rescue for flagged rows (grid-stride over candidates)
// ---------------------------------------------------------------------------
__global__ __launch_bounds__(256) void vq_rescue_kernel(
    const float* __restrict__ x, const float* __restrict__ e,
    const double* __restrict__ ee64, const int* __restrict__ cand,
    const int* __restrict__ cntp, float* __restrict__ idx_out) {
  __shared__ float  xrow[HD_];
  __shared__ double rv[256];
  __shared__ int    ri[256];
  int count = *cntp;
  if (count > CAND_CAP) count = CAND_CAP;
  for (int c = blockIdx.x; c < count; c += gridDim.x) {
    int nh = cand[c];
    int n = nh >> 2, h = nh & 3;
    if (threadIdx.x < HD_)
      xrow[threadIdx.x] = x[((size_t)n * HEADS + h) * HD_ + threadIdx.x];
    __syncthreads();
    const float* eh = e + (size_t)h * HD_ * KC;
    double bv = __builtin_inf();
    int bi = 0;
    for (int k = threadIdx.x; k < KC; k += 256) {
      double dot = 0.0;
#pragma unroll 8
      for (int d = 0; d < HD_; ++d)
        dot = fma((double)xrow[d], (double)eh[(size_t)d * KC + k], dot);
      double v = ee64[h * KC + k] - 2.0 * dot;  // ||x||^2 row-uniform: dropped
      if (v < bv || (v == bv && k < bi)) { bv = v; bi = k; }
    }
    rv[threadIdx.x] = bv; ri[threadIdx.x] = bi;
    __syncthreads();
    for (int s2 = 128; s2 > 0; s2 >>= 1) {
      if (threadIdx.x < s2) {
        double v2 = rv[threadIdx.x + s2]; int idx2 = ri[threadIdx.x + s2];
        if (v2 < rv[threadIdx.x] ||
            (v2 == rv[threadIdx.x] && idx2 < ri[threadIdx.x])) {
          rv[threadIdx.x] = v2; ri[threadIdx.x] = idx2;
        }
      }
      __syncthreads();
    }
    if (threadIdx.x == 0) idx_out[(size_t)n * HEADS + h] = (float)ri[0];
    __syncthreads();
  }
}

// ---------------------------------------------------------------------------
// Kernel 3: gather quantize output + L1 mean (atomic per block)
// ---------------------------------------------------------------------------
__global__ __launch_bounds__(256) void vq_gather_kernel(
    const float* __restrict__ x, const float* __restrict__ e,
    const float* __restrict__ idxf, float* __restrict__ out,
    float* __restrict__ diffp) {
  const size_t stride = (size_t)gridDim.x * 256;
  float local = 0.f;
  for (size_t f = (size_t)blockIdx.x * 256 + threadIdx.x; f < XELEMS; f += stride) {
    int n  = (int)(f >> 9);
    int rh = (int)(f & 511);
    int h  = rh >> 7;
    int d  = rh & 127;
    int k  = (int)idxf[n * HEADS + h];
    float q  = e[(size_t)(h * HD_ + d) * KC + k];
    float xv = x[f];
    out[f] = q;
    local += fabsf(xv - q);
  }
  for (int o = 32; o > 0; o >>= 1) local += __shfl_down(local, o, 64);
  __shared__ float ws[4];
  int lane = threadIdx.x & 63, w = threadIdx.x >> 6;
  if (lane == 0) ws[w] = local;
  __syncthreads();
  if (threadIdx.x == 0) {
    float s = (ws[0] + ws[1] + ws[2] + ws[3]) * (1.0f / 8388608.0f);
    atomicAdd(diffp, s);
  }
}

// ---------------------------------------------------------------------------
extern "C" void kernel_launch(void* const* d_in, const int* in_sizes, int n_in,
                              void* d_out, int out_size, void* d_ws, size_t ws_size,
                              hipStream_t stream) {
  const float* x = (const float*)d_in[0];
  const float* e = (const float*)d_in[1];
  float* out   = (float*)d_out;
  float*  ee32 = out + EE32_OFF;            // scratch in quantize region
  double* ee64 = (double*)(out + EE64_OFF); // byte offset 65536, 8-aligned
  int*    cnt  = (int*)(out + CNT_OFF);
  int*    cand = (int*)(out + CAND_OFF);
  float* diffp = out + DIFFOFF;
  float* idxp  = out + IDXOFF;

  hipMemsetAsync(diffp, 0, sizeof(float), stream);
  hipMemsetAsync(cnt, 0, sizeof(int), stream);
  vq_ee_kernel<<<dim3(KC / 256, HEADS), 256, 0, stream>>>(e, ee32, ee64);
  vq_argmin_kernel<<<dim3(N_TOK / MT, HEADS), 512, 0, stream>>>(x, e, ee32, idxp, cnt, cand);
  vq_rescue_kernel<<<128, 256, 0, stream>>>(x, e, ee64, cand, cnt, idxp);
  vq_gather_kernel<<<2048, 256, 0, stream>>>(x, e, idxp, out, diffp);
}

// Round 10
// 613.145 us; speedup vs baseline: 2.2410x; 2.2410x over previous
//
#include <hip/hip_runtime.h>

// Problem constants (B=8, S=2048, D=512, H=4, HD=128, K=4096)
#define N_TOK 16384
#define HEADS 4
#define HD_   128
#define KC    4096
#define XELEMS 8388608
#define DIFFOFF 8388608
#define IDXOFF  8388609

// Scratch layout inside d_out's quantize region (floats; gather overwrites all):
#define EE32_OFF 0            // 16384 floats
#define EE64_OFF 16384        // 16384 doubles (byte 65536, 8-aligned)
#define CNT_OFF  49152        // 1 int
#define CAND_OFF 49153        // up to 65536 ints
#define CAND_CAP 65536
#define EBH_OFF  131072       // bf16-hi plane: 2,097,152 u16 = 1,048,576 floats
#define EBL_OFF  1179648      // bf16-lo plane

#define MARGIN 3.0f           // mfma-screen worst error ~0.1 -> 30x slack

typedef unsigned short u16;
typedef __attribute__((ext_vector_type(8))) short bf16x8;  // 8 bf16 (4 VGPRs)
typedef __attribute__((ext_vector_type(4))) float f32x4;
typedef __attribute__((ext_vector_type(4))) unsigned int u32x4;

#define MFMA_BF16(ACC, A, B) \
  (ACC) = __builtin_amdgcn_mfma_f32_16x16x32_bf16((A), (B), (ACC), 0, 0, 0)

// RNE float->bf16 of v0,v1 (hi) and residuals (lo), packed 2x16.
__device__ inline void cvt2(float v0, float v1, unsigned& hi, unsigned& lo) {
  unsigned u0 = __float_as_uint(v0), u1 = __float_as_uint(v1);
  unsigned h0 = (u0 + 0x7fffu + ((u0 >> 16) & 1)) & 0xffff0000u;
  unsigned h1 = (u1 + 0x7fffu + ((u1 >> 16) & 1)) & 0xffff0000u;
  float r0 = v0 - __uint_as_float(h0);
  float r1 = v1 - __uint_as_float(h1);
  unsigned w0 = __float_as_uint(r0), w1 = __float_as_uint(r1);
  unsigned l0 = (w0 + 0x7fffu + ((w0 >> 16) & 1)) & 0xffff0000u;
  unsigned l1 = (w1 + 0x7fffu + ((w1 >> 16) & 1)) & 0xffff0000u;
  hi = (h0 >> 16) | (h1 & 0xffff0000u);
  lo = (l0 >> 16) | (l1 & 0xffff0000u);
}

// ---------------------------------------------------------------------------
// Pre-pass: per (head, 64-code tile): fp64 ee, and planar bf16 hi/lo codebook
// transposed to code-major [h][code][d] (feeds MFMA B-frags as 8-consecutive-d).
// ---------------------------------------------------------------------------
__global__ __launch_bounds__(256) void vq_prepass(const float* __restrict__ e,
                                                  float* __restrict__ ee32,
                                                  double* __restrict__ ee64,
                                                  u16* __restrict__ ebh,
                                                  u16* __restrict__ ebl) {
  const int h = blockIdx.y, c0 = blockIdx.x * 64;
  const int t = threadIdx.x, c = t >> 2, ds = t & 3;
  const int code = c0 + c;
  const float* eh = e + (size_t)h * HD_ * KC;
  unsigned hp[16], lq[16];
  double s = 0.0;
#pragma unroll
  for (int j2 = 0; j2 < 16; ++j2) {
    int d0 = ds * 32 + j2 * 2;
    float v0 = eh[(size_t)d0 * KC + code];
    float v1 = eh[(size_t)(d0 + 1) * KC + code];
    s = fma((double)v0, (double)v0, s);
    s = fma((double)v1, (double)v1, s);
    cvt2(v0, v1, hp[j2], lq[j2]);
  }
  u32x4* WH = (u32x4*)(ebh + ((size_t)h * KC + code) * HD_ + ds * 32);
  u32x4* WL = (u32x4*)(ebl + ((size_t)h * KC + code) * HD_ + ds * 32);
#pragma unroll
  for (int q = 0; q < 4; ++q) {
    WH[q] = u32x4{hp[4 * q], hp[4 * q + 1], hp[4 * q + 2], hp[4 * q + 3]};
    WL[q] = u32x4{lq[4 * q], lq[4 * q + 1], lq[4 * q + 2], lq[4 * q + 3]};
  }
  __shared__ double pr[64][4];
  pr[c][ds] = s;
  __syncthreads();
  if (t < 64) {
    double tot = (pr[t][0] + pr[t][1]) + (pr[t][2] + pr[t][3]);
    ee64[h * KC + c0 + t] = tot;
    ee32[h * KC + c0 + t] = (float)tot;
  }
}

// ---------------------------------------------------------------------------
// MFMA screening argmin. 512 thr / 8 waves; tile 128 tokens x 4096 codes.
// Wave tile 64x64 (2M x 4N waves). dot via 3-pass bf16 split; dist = ee-2dot.
// K-step 32, e-tiles double-buffered, issue-early/write-late reg staging.
// Per-row best+second tracked in regs; near-ties (<MARGIN) -> fp64 rescue.
// ---------------------------------------------------------------------------
__global__ __launch_bounds__(512, 2) void vq_mfma_kernel(
    const float* __restrict__ x, const u16* __restrict__ ebh,
    const u16* __restrict__ ebl, const float* __restrict__ ee,
    float* __restrict__ idx_out, int* __restrict__ cnt, int* __restrict__ cand) {
  __shared__ u16 xh[128][136];        // 272B rows: frag reads 2-way (free)
  __shared__ u16 xl[128][136];
  __shared__ u16 es[2][2][256][40];   // [buf][plane][code][32k+pad] 80B rows

  const int t = threadIdx.x;
  const int lane = t & 63, w = t >> 6;
  const int h = blockIdx.y, n0 = blockIdx.x * 128;
  const int wm = w >> 2, wn = w & 3;
  const int l15 = lane & 15, lp = lane >> 4;

  // ---- stage x: load fp32 rows, split to bf16 hi/lo in LDS (once)
  {
    int r = t >> 2, ds = t & 3;
    const float* xp = x + ((size_t)(n0 + r) * HEADS + h) * HD_ + ds * 32;
    u16* dh = &xh[r][ds * 32];
    u16* dl = &xl[r][ds * 32];
#pragma unroll
    for (int j8 = 0; j8 < 4; ++j8) {
      float4 a = *(const float4*)(xp + j8 * 8);
      float4 b = *(const float4*)(xp + j8 * 8 + 4);
      unsigned h0, h1, h2, h3, l0, l1, l2, l3;
      cvt2(a.x, a.y, h0, l0); cvt2(a.z, a.w, h1, l1);
      cvt2(b.x, b.y, h2, l2); cvt2(b.z, b.w, h3, l3);
      *(u32x4*)(dh + j8 * 8) = u32x4{h0, h1, h2, h3};
      *(u32x4*)(dl + j8 * 8) = u32x4{l0, l1, l2, l3};
    }
  }

  // ---- e staging helpers (reg-staged; step s: chunk=s>>2, ks=s&3)
  const u16* ebh_h = ebh + (size_t)h * KC * HD_;
  const u16* ebl_h = ebl + (size_t)h * KC * HD_;
  const int slot0 = t * 2;
  const int sc0 = slot0 >> 2, sk0 = slot0 & 3;
  const int sc1 = (slot0 + 1) >> 2, sk1 = (slot0 + 1) & 3;
  u32x4 sregs[4];
  auto LD = [&](int s) {
    int cg = (s >> 2) * 256, ks = s & 3;
    size_t o0 = (size_t)(cg + sc0) * HD_ + ks * 32 + sk0 * 8;
    size_t o1 = (size_t)(cg + sc1) * HD_ + ks * 32 + sk1 * 8;
    sregs[0] = *(const u32x4*)(ebh_h + o0);
    sregs[1] = *(const u32x4*)(ebh_h + o1);
    sregs[2] = *(const u32x4*)(ebl_h + o0);
    sregs[3] = *(const u32x4*)(ebl_h + o1);
  };
  auto ST = [&](int buf) {
    *(u32x4*)&es[buf][0][sc0][sk0 * 8] = sregs[0];
    *(u32x4*)&es[buf][0][sc1][sk1 * 8] = sregs[1];
    *(u32x4*)&es[buf][1][sc0][sk0 * 8] = sregs[2];
    *(u32x4*)&es[buf][1][sc1][sk1 * 8] = sregs[3];
  };

  LD(0); ST(0);
  __syncthreads();

  float b1v[16], b2v[16];
  int i1v[16];
#pragma unroll
  for (int r = 0; r < 16; ++r) {
    b1v[r] = __builtin_inff(); b2v[r] = __builtin_inff(); i1v[r] = 0;
  }

  f32x4 acc[4][4];
  for (int chunk = 0; chunk < 16; ++chunk) {
#pragma unroll
    for (int m = 0; m < 4; ++m)
#pragma unroll
      for (int n = 0; n < 4; ++n) acc[m][n] = f32x4{0.f, 0.f, 0.f, 0.f};

    float eev[4];
    {
      const float* eep = ee + (size_t)h * KC + chunk * 256 + wn * 64 + l15;
#pragma unroll
      for (int n = 0; n < 4; ++n) eev[n] = eep[n * 16];
    }

#pragma unroll
    for (int ks = 0; ks < 4; ++ks) {
      const int step = chunk * 4 + ks;
      const bool pf = (step + 1) < 64;
      if (pf) LD(step + 1);                  // issue next-step global loads
      const int buf = step & 1;
      bf16x8 ah[4], al[4], bh[4], bl[4];
#pragma unroll
      for (int m = 0; m < 4; ++m) {
        int row = wm * 64 + m * 16 + l15;
        ah[m] = *(const bf16x8*)&xh[row][ks * 32 + lp * 8];
        al[m] = *(const bf16x8*)&xl[row][ks * 32 + lp * 8];
      }
#pragma unroll
      for (int n = 0; n < 4; ++n) {
        int cc = wn * 64 + n * 16 + l15;
        bh[n] = *(const bf16x8*)&es[buf][0][cc][lp * 8];
        bl[n] = *(const bf16x8*)&es[buf][1][cc][lp * 8];
      }
#pragma unroll
      for (int m = 0; m < 4; ++m)
#pragma unroll
        for (int n = 0; n < 4; ++n) {
          MFMA_BF16(acc[m][n], ah[m], bh[n]);  // xh*eh
          MFMA_BF16(acc[m][n], ah[m], bl[n]);  // xh*el
          MFMA_BF16(acc[m][n], al[m], bh[n]);  // xl*eh
        }
      if (pf) ST((step + 1) & 1);              // write-late after compute
      __syncthreads();
    }

    // chunk epilogue: dist + best/second update (regs only)
    const int colb = chunk * 256 + wn * 64 + l15;
#pragma unroll
    for (int m = 0; m < 4; ++m)
#pragma unroll
      for (int i = 0; i < 4; ++i) {
        const int r = m * 4 + i;
#pragma unroll
        for (int n = 0; n < 4; ++n) {
          float val = fmaf(-2.0f, acc[m][n][i], eev[n]);
          bool lt = val < b1v[r];
          b2v[r] = lt ? b1v[r] : fminf(b2v[r], val);
          i1v[r] = lt ? (colb + n * 16) : i1v[r];
          b1v[r] = lt ? val : b1v[r];
        }
      }
  }

  // ---- reduce across the 16 col-lanes (l15) via shuffles
#pragma unroll
  for (int off = 8; off; off >>= 1) {
#pragma unroll
    for (int r = 0; r < 16; ++r) {
      float ob1 = __shfl_xor(b1v[r], off, 64);
      float ob2 = __shfl_xor(b2v[r], off, 64);
      int oi1 = __shfl_xor(i1v[r], off, 64);
      bool win = (ob1 < b1v[r]) || (ob1 == b1v[r] && oi1 < i1v[r]);
      float nb2 = win ? fminf(b1v[r], ob2) : fminf(b2v[r], ob1);
      b1v[r] = win ? ob1 : b1v[r];
      i1v[r] = win ? oi1 : i1v[r];
      b2v[r] = nb2;
    }
  }

  // ---- cross-wave (4 N-waves) reduce via LDS (aliases es; frag reads done)
  float* red = (float*)&es[0][0][0][0];        // [row128][wn4][3]
  if (l15 == 0) {
#pragma unroll
    for (int r = 0; r < 16; ++r) {
      int row = wm * 64 + (r >> 2) * 16 + lp * 4 + (r & 3);
      float* p = red + (row * 4 + wn) * 3;
      p[0] = b1v[r]; p[1] = b2v[r]; ((int*)p)[2] = i1v[r];
    }
  }
  __syncthreads();
  if (t < 128) {
    float* p = red + (t * 4) * 3;
    float fb1 = p[0], fb2 = p[1];
    int fi1 = ((int*)p)[2];
#pragma unroll
    for (int q = 1; q < 4; ++q) {
      float* pq = red + (t * 4 + q) * 3;
      float ob1 = pq[0], ob2 = pq[1];
      int oi1 = ((int*)pq)[2];
      bool win = (ob1 < fb1) || (ob1 == fb1 && oi1 < fi1);
      float nb2 = win ? fminf(fb1, ob2) : fminf(fb2, ob1);
      fb1 = win ? ob1 : fb1;
      fi1 = win ? oi1 : fi1;
      fb2 = nb2;
    }
    idx_out[(size_t)(n0 + t) * HEADS + h] = (float)fi1;
    if (fb2 - fb1 < MARGIN) {
      int slot = atomicAdd(cnt, 1);
      if (slot < CAND_CAP) cand[slot] = (n0 + t) * HEADS + h;
    }
  }
}

// ---------------------------------------------------------------------------
// fp64 exact rescue for flagged rows
// ---------------------------------------------------------------------------
__global__ __launch_bounds__(256) void vq_rescue_kernel(
    const float* __restrict__ x, const float* __restrict__ e,
    const double* __restrict__ ee64, const int* __restrict__ cand,
    const int* __restrict__ cntp, float* __restrict__ idx_out) {
  __shared__ float  xrow[HD_];
  __shared__ double rv[256];
  __shared__ int    ri[256];
  int count = *cntp;
  if (count > CAND_CAP) count = CAND_CAP;
  for (int c = blockIdx.x; c < count; c += gridDim.x) {
    int nh = cand[c];
    int n = nh >> 2, h = nh & 3;
    if (threadIdx.x < HD_)
      xrow[threadIdx.x] = x[((size_t)n * HEADS + h) * HD_ + threadIdx.x];
    __syncthreads();
    const float* eh = e + (size_t)h * HD_ * KC;
    double bv = __builtin_inf();
    int bi = 0;
    for (int k = threadIdx.x; k < KC; k += 256) {
      double dot = 0.0;
#pragma unroll 8
      for (int d = 0; d < HD_; ++d)
        dot = fma((double)xrow[d], (double)eh[(size_t)d * KC + k], dot);
      double v = ee64[h * KC + k] - 2.0 * dot;
      if (v < bv || (v == bv && k < bi)) { bv = v; bi = k; }
    }
    rv[threadIdx.x] = bv; ri[threadIdx.x] = bi;
    __syncthreads();
    for (int s2 = 128; s2 > 0; s2 >>= 1) {
      if (threadIdx.x < s2) {
        double v2 = rv[threadIdx.x + s2]; int idx2 = ri[threadIdx.x + s2];
        if (v2 < rv[threadIdx.x] ||
            (v2 == rv[threadIdx.x] && idx2 < ri[threadIdx.x])) {
          rv[threadIdx.x] = v2; ri[threadIdx.x] = idx2;
        }
      }
      __syncthreads();
    }
    if (threadIdx.x == 0) idx_out[(size_t)n * HEADS + h] = (float)ri[0];
    __syncthreads();
  }
}

// ---------------------------------------------------------------------------
// Gather quantize output + L1 mean
// ---------------------------------------------------------------------------
__global__ __launch_bounds__(256) void vq_gather_kernel(
    const float* __restrict__ x, const float* __restrict__ e,
    const float* __restrict__ idxf, float* __restrict__ out,
    float* __restrict__ diffp) {
  const size_t stride = (size_t)gridDim.x * 256;
  float local = 0.f;
  for (size_t f = (size_t)blockIdx.x * 256 + threadIdx.x; f < XELEMS; f += stride) {
    int n  = (int)(f >> 9);
    int rh = (int)(f & 511);
    int h  = rh >> 7;
    int d  = rh & 127;
    int k  = (int)idxf[n * HEADS + h];
    float q  = e[(size_t)(h * HD_ + d) * KC + k];
    float xv = x[f];
    out[f] = q;
    local += fabsf(xv - q);
  }
  for (int o = 32; o > 0; o >>= 1) local += __shfl_down(local, o, 64);
  __shared__ float ws[4];
  int lane = threadIdx.x & 63, wv = threadIdx.x >> 6;
  if (lane == 0) ws[wv] = local;
  __syncthreads();
  if (threadIdx.x == 0) {
    float s = (ws[0] + ws[1] + ws[2] + ws[3]) * (1.0f / 8388608.0f);
    atomicAdd(diffp, s);
  }
}

// ---------------------------------------------------------------------------
extern "C" void kernel_launch(void* const* d_in, const int* in_sizes, int n_in,
                              void* d_out, int out_size, void* d_ws, size_t ws_size,
                              hipStream_t stream) {
  const float* x = (const float*)d_in[0];
  const float* e = (const float*)d_in[1];
  float* out   = (float*)d_out;
  float*  ee32 = out + EE32_OFF;
  double* ee64 = (double*)(out + EE64_OFF);
  int*    cnt  = (int*)(out + CNT_OFF);
  int*    cand = (int*)(out + CAND_OFF);
  u16*    ebh  = (u16*)(out + EBH_OFF);
  u16*    ebl  = (u16*)(out + EBL_OFF);
  float* diffp = out + DIFFOFF;
  float* idxp  = out + IDXOFF;

  hipMemsetAsync(diffp, 0, sizeof(float), stream);
  hipMemsetAsync(cnt, 0, sizeof(int), stream);
  vq_prepass<<<dim3(KC / 64, HEADS), 256, 0, stream>>>(e, ee32, ee64, ebh, ebl);
  vq_mfma_kernel<<<dim3(N_TOK / 128, HEADS), 512, 0, stream>>>(x, ebh, ebl, ee32, idxp, cnt, cand);
  vq_rescue_kernel<<<128, 256, 0, stream>>>(x, e, ee64, cand, cnt, idxp);
  vq_gather_kernel<<<2048, 256, 0, stream>>>(x, e, idxp, out, diffp);
}

// Round 11
// 383.757 us; speedup vs baseline: 3.5806x; 1.5977x over previous
//
#include <hip/hip_runtime.h>

// Problem constants (B=8, S=2048, D=512, H=4, HD=128, K=4096)
#define N_TOK 16384
#define HEADS 4
#define HD_   128
#define KC    4096
#define XELEMS 8388608
#define DIFFOFF 8388608
#define IDXOFF  8388609

// Scratch layout inside d_out's quantize region (floats; gather overwrites all):
#define EE32_OFF 0            // 16384 floats
#define EE64_OFF 16384        // 16384 doubles (byte 65536, 8-aligned)
#define CNT_OFF  49152        // 1 int
#define CAND_OFF 49153        // up to 65536 ints
#define CAND_CAP 65536
#define EBH_OFF  131072       // bf16-hi plane: 2,097,152 u16 = 1,048,576 floats
#define EBL_OFF  1179648      // bf16-lo plane

#define MARGIN 0.75f          // screen error budget ~0.012 worst; >=2E needed -> 30x slack

typedef unsigned short u16;
typedef __attribute__((ext_vector_type(8))) short bf16x8;  // 8 bf16 (4 VGPRs)
typedef __attribute__((ext_vector_type(4))) float f32x4;
typedef __attribute__((ext_vector_type(4))) unsigned int u32x4;

#define MFMA_BF16(ACC, A, B) \
  (ACC) = __builtin_amdgcn_mfma_f32_16x16x32_bf16((A), (B), (ACC), 0, 0, 0)

// RNE float->bf16 of v0,v1 (hi) and residuals (lo), packed 2x16.
__device__ inline void cvt2(float v0, float v1, unsigned& hi, unsigned& lo) {
  unsigned u0 = __float_as_uint(v0), u1 = __float_as_uint(v1);
  unsigned h0 = (u0 + 0x7fffu + ((u0 >> 16) & 1)) & 0xffff0000u;
  unsigned h1 = (u1 + 0x7fffu + ((u1 >> 16) & 1)) & 0xffff0000u;
  float r0 = v0 - __uint_as_float(h0);
  float r1 = v1 - __uint_as_float(h1);
  unsigned w0 = __float_as_uint(r0), w1 = __float_as_uint(r1);
  unsigned l0 = (w0 + 0x7fffu + ((w0 >> 16) & 1)) & 0xffff0000u;
  unsigned l1 = (w1 + 0x7fffu + ((w1 >> 16) & 1)) & 0xffff0000u;
  hi = (h0 >> 16) | (h1 & 0xffff0000u);
  lo = (l0 >> 16) | (l1 & 0xffff0000u);
}

// ---------------------------------------------------------------------------
// Pre-pass: per (head, 64-code tile): fp64 ee, and planar bf16 hi/lo codebook
// transposed to code-major [h][code][d] (feeds MFMA B-frags as 8-consecutive-d).
// ---------------------------------------------------------------------------
__global__ __launch_bounds__(256) void vq_prepass(const float* __restrict__ e,
                                                  float* __restrict__ ee32,
                                                  double* __restrict__ ee64,
                                                  u16* __restrict__ ebh,
                                                  u16* __restrict__ ebl) {
  const int h = blockIdx.y, c0 = blockIdx.x * 64;
  const int t = threadIdx.x, c = t >> 2, ds = t & 3;
  const int code = c0 + c;
  const float* eh = e + (size_t)h * HD_ * KC;
  unsigned hp[16], lq[16];
  double s = 0.0;
#pragma unroll
  for (int j2 = 0; j2 < 16; ++j2) {
    int d0 = ds * 32 + j2 * 2;
    float v0 = eh[(size_t)d0 * KC + code];
    float v1 = eh[(size_t)(d0 + 1) * KC + code];
    s = fma((double)v0, (double)v0, s);
    s = fma((double)v1, (double)v1, s);
    cvt2(v0, v1, hp[j2], lq[j2]);
  }
  u32x4* WH = (u32x4*)(ebh + ((size_t)h * KC + code) * HD_ + ds * 32);
  u32x4* WL = (u32x4*)(ebl + ((size_t)h * KC + code) * HD_ + ds * 32);
#pragma unroll
  for (int q = 0; q < 4; ++q) {
    WH[q] = u32x4{hp[4 * q], hp[4 * q + 1], hp[4 * q + 2], hp[4 * q + 3]};
    WL[q] = u32x4{lq[4 * q], lq[4 * q + 1], lq[4 * q + 2], lq[4 * q + 3]};
  }
  __shared__ double pr[64][4];
  pr[c][ds] = s;
  __syncthreads();
  if (t < 64) {
    double tot = (pr[t][0] + pr[t][1]) + (pr[t][2] + pr[t][3]);
    ee64[h * KC + c0 + t] = tot;
    ee32[h * KC + c0 + t] = (float)tot;
  }
}

// ---------------------------------------------------------------------------
// MFMA screening argmin. 512 thr / 8 waves; tile 128 tokens x 4096 codes.
// Wave tile 64x64 (2M x 4N waves). dot via 3-pass bf16 split; dist = ee-2dot.
// K-step 32, e-tiles double-buffered, issue-early/write-late reg staging.
// Per-row best+second tracked in regs; near-ties (<MARGIN) -> fp64 rescue.
// ---------------------------------------------------------------------------
__global__ __launch_bounds__(512, 2) void vq_mfma_kernel(
    const float* __restrict__ x, const u16* __restrict__ ebh,
    const u16* __restrict__ ebl, const float* __restrict__ ee,
    float* __restrict__ idx_out, int* __restrict__ cnt, int* __restrict__ cand) {
  __shared__ u16 xh[128][136];        // 272B rows: frag reads 2-way (free)
  __shared__ u16 xl[128][136];
  __shared__ u16 es[2][2][256][40];   // [buf][plane][code][32k+pad] 80B rows

  const int t = threadIdx.x;
  const int lane = t & 63, w = t >> 6;
  const int h = blockIdx.y, n0 = blockIdx.x * 128;
  const int wm = w >> 2, wn = w & 3;
  const int l15 = lane & 15, lp = lane >> 4;

  // ---- stage x: load fp32 rows, split to bf16 hi/lo in LDS (once)
  {
    int r = t >> 2, ds = t & 3;
    const float* xp = x + ((size_t)(n0 + r) * HEADS + h) * HD_ + ds * 32;
    u16* dh = &xh[r][ds * 32];
    u16* dl = &xl[r][ds * 32];
#pragma unroll
    for (int j8 = 0; j8 < 4; ++j8) {
      float4 a = *(const float4*)(xp + j8 * 8);
      float4 b = *(const float4*)(xp + j8 * 8 + 4);
      unsigned h0, h1, h2, h3, l0, l1, l2, l3;
      cvt2(a.x, a.y, h0, l0); cvt2(a.z, a.w, h1, l1);
      cvt2(b.x, b.y, h2, l2); cvt2(b.z, b.w, h3, l3);
      *(u32x4*)(dh + j8 * 8) = u32x4{h0, h1, h2, h3};
      *(u32x4*)(dl + j8 * 8) = u32x4{l0, l1, l2, l3};
    }
  }

  // ---- e staging helpers (reg-staged; step s: chunk=s>>2, ks=s&3)
  const u16* ebh_h = ebh + (size_t)h * KC * HD_;
  const u16* ebl_h = ebl + (size_t)h * KC * HD_;
  const int slot0 = t * 2;
  const int sc0 = slot0 >> 2, sk0 = slot0 & 3;
  const int sc1 = (slot0 + 1) >> 2, sk1 = (slot0 + 1) & 3;
  u32x4 sregs[4];
  auto LD = [&](int s) {
    int cg = (s >> 2) * 256, ks = s & 3;
    size_t o0 = (size_t)(cg + sc0) * HD_ + ks * 32 + sk0 * 8;
    size_t o1 = (size_t)(cg + sc1) * HD_ + ks * 32 + sk1 * 8;
    sregs[0] = *(const u32x4*)(ebh_h + o0);
    sregs[1] = *(const u32x4*)(ebh_h + o1);
    sregs[2] = *(const u32x4*)(ebl_h + o0);
    sregs[3] = *(const u32x4*)(ebl_h + o1);
  };
  auto ST = [&](int buf) {
    *(u32x4*)&es[buf][0][sc0][sk0 * 8] = sregs[0];
    *(u32x4*)&es[buf][0][sc1][sk1 * 8] = sregs[1];
    *(u32x4*)&es[buf][1][sc0][sk0 * 8] = sregs[2];
    *(u32x4*)&es[buf][1][sc1][sk1 * 8] = sregs[3];
  };

  LD(0); ST(0);
  __syncthreads();

  float b1v[16], b2v[16];
  int i1v[16];
#pragma unroll
  for (int r = 0; r < 16; ++r) {
    b1v[r] = __builtin_inff(); b2v[r] = __builtin_inff(); i1v[r] = 0;
  }

  f32x4 acc[4][4];
  for (int chunk = 0; chunk < 16; ++chunk) {
#pragma unroll
    for (int m = 0; m < 4; ++m)
#pragma unroll
      for (int n = 0; n < 4; ++n) acc[m][n] = f32x4{0.f, 0.f, 0.f, 0.f};

    float eev[4];
    {
      const float* eep = ee + (size_t)h * KC + chunk * 256 + wn * 64 + l15;
#pragma unroll
      for (int n = 0; n < 4; ++n) eev[n] = eep[n * 16];
    }

#pragma unroll
    for (int ks = 0; ks < 4; ++ks) {
      const int step = chunk * 4 + ks;
      const bool pf = (step + 1) < 64;
      if (pf) LD(step + 1);                  // issue next-step global loads
      const int buf = step & 1;
      bf16x8 ah[4], al[4], bh[4], bl[4];
#pragma unroll
      for (int m = 0; m < 4; ++m) {
        int row = wm * 64 + m * 16 + l15;
        ah[m] = *(const bf16x8*)&xh[row][ks * 32 + lp * 8];
        al[m] = *(const bf16x8*)&xl[row][ks * 32 + lp * 8];
      }
#pragma unroll
      for (int n = 0; n < 4; ++n) {
        int cc = wn * 64 + n * 16 + l15;
        bh[n] = *(const bf16x8*)&es[buf][0][cc][lp * 8];
        bl[n] = *(const bf16x8*)&es[buf][1][cc][lp * 8];
      }
#pragma unroll
      for (int m = 0; m < 4; ++m)
#pragma unroll
        for (int n = 0; n < 4; ++n) {
          MFMA_BF16(acc[m][n], ah[m], bh[n]);  // xh*eh
          MFMA_BF16(acc[m][n], ah[m], bl[n]);  // xh*el
          MFMA_BF16(acc[m][n], al[m], bh[n]);  // xl*eh
        }
      if (pf) ST((step + 1) & 1);              // write-late after compute
      __syncthreads();
    }

    // chunk epilogue: dist + best/second update (regs only)
    const int colb = chunk * 256 + wn * 64 + l15;
#pragma unroll
    for (int m = 0; m < 4; ++m)
#pragma unroll
      for (int i = 0; i < 4; ++i) {
        const int r = m * 4 + i;
#pragma unroll
        for (int n = 0; n < 4; ++n) {
          float val = fmaf(-2.0f, acc[m][n][i], eev[n]);
          bool lt = val < b1v[r];
          b2v[r] = lt ? b1v[r] : fminf(b2v[r], val);
          i1v[r] = lt ? (colb + n * 16) : i1v[r];
          b1v[r] = lt ? val : b1v[r];
        }
      }
  }

  // ---- reduce across the 16 col-lanes (l15) via shuffles
#pragma unroll
  for (int off = 8; off; off >>= 1) {
#pragma unroll
    for (int r = 0; r < 16; ++r) {
      float ob1 = __shfl_xor(b1v[r], off, 64);
      float ob2 = __shfl_xor(b2v[r], off, 64);
      int oi1 = __shfl_xor(i1v[r], off, 64);
      bool win = (ob1 < b1v[r]) || (ob1 == b1v[r] && oi1 < i1v[r]);
      float nb2 = win ? fminf(b1v[r], ob2) : fminf(b2v[r], ob1);
      b1v[r] = win ? ob1 : b1v[r];
      i1v[r] = win ? oi1 : i1v[r];
      b2v[r] = nb2;
    }
  }

  // ---- cross-wave (4 N-waves) reduce via LDS (aliases es; frag reads done)
  float* red = (float*)&es[0][0][0][0];        // [row128][wn4][3]
  if (l15 == 0) {
#pragma unroll
    for (int r = 0; r < 16; ++r) {
      int row = wm * 64 + (r >> 2) * 16 + lp * 4 + (r & 3);
      float* p = red + (row * 4 + wn) * 3;
      p[0] = b1v[r]; p[1] = b2v[r]; ((int*)p)[2] = i1v[r];
    }
  }
  __syncthreads();
  if (t < 128) {
    float* p = red + (t * 4) * 3;
    float fb1 = p[0], fb2 = p[1];
    int fi1 = ((int*)p)[2];
#pragma unroll
    for (int q = 1; q < 4; ++q) {
      float* pq = red + (t * 4 + q) * 3;
      float ob1 = pq[0], ob2 = pq[1];
      int oi1 = ((int*)pq)[2];
      bool win = (ob1 < fb1) || (ob1 == fb1 && oi1 < fi1);
      float nb2 = win ? fminf(fb1, ob2) : fminf(fb2, ob1);
      fb1 = win ? ob1 : fb1;
      fi1 = win ? oi1 : fi1;
      fb2 = nb2;
    }
    idx_out[(size_t)(n0 + t) * HEADS + h] = (float)fi1;
    if (fb2 - fb1 < MARGIN) {
      int slot = atomicAdd(cnt, 1);
      if (slot < CAND_CAP) cand[slot] = (n0 + t) * HEADS + h;
    }
  }
}

// ---------------------------------------------------------------------------
// fp64 exact rescue for flagged rows. One candidate per block (grid-stride).
// d-loop outer, 16 fp64 accumulators (code slots k = j*256 + t): per-d loads
// are 16 independent coalesced reads -> issue-limited streaming, not latency.
// ---------------------------------------------------------------------------
__global__ __launch_bounds__(256) void vq_rescue_kernel(
    const float* __restrict__ x, const float* __restrict__ e,
    const double* __restrict__ ee64, const int* __restrict__ cand,
    const int* __restrict__ cntp, float* __restrict__ idx_out) {
  __shared__ float  xrow[HD_];
  __shared__ double rv[256];
  __shared__ int    ri[256];
  int count = *cntp;
  if (count > CAND_CAP) count = CAND_CAP;
  const int t = threadIdx.x;
  for (int c = blockIdx.x; c < count; c += gridDim.x) {
    int nh = cand[c];
    int n = nh >> 2, h = nh & 3;
    if (t < HD_) xrow[t] = x[((size_t)n * HEADS + h) * HD_ + t];
    __syncthreads();
    const float* eh = e + (size_t)h * HD_ * KC;

    double acc[16];
#pragma unroll
    for (int j = 0; j < 16; ++j) acc[j] = 0.0;
    for (int d = 0; d < HD_; ++d) {
      double xd = (double)xrow[d];
      const float* row = eh + (size_t)d * KC + t;
#pragma unroll
      for (int j = 0; j < 16; ++j)
        acc[j] = fma(xd, (double)row[j * 256], acc[j]);
    }

    double bv = __builtin_inf();
    int bi = 0;
#pragma unroll
    for (int j = 0; j < 16; ++j) {
      int k = j * 256 + t;
      double v = ee64[h * KC + k] - 2.0 * acc[j];  // ||x||^2 row-uniform: dropped
      if (v < bv || (v == bv && k < bi)) { bv = v; bi = k; }
    }

    rv[t] = bv; ri[t] = bi;
    __syncthreads();
    for (int s2 = 128; s2 > 0; s2 >>= 1) {
      if (t < s2) {
        double v2 = rv[t + s2]; int idx2 = ri[t + s2];
        if (v2 < rv[t] || (v2 == rv[t] && idx2 < ri[t])) {
          rv[t] = v2; ri[t] = idx2;
        }
      }
      __syncthreads();
    }
    if (t == 0) idx_out[(size_t)n * HEADS + h] = (float)ri[0];
    __syncthreads();
  }
}

// ---------------------------------------------------------------------------
// Gather quantize output + L1 mean
// ---------------------------------------------------------------------------
__global__ __launch_bounds__(256) void vq_gather_kernel(
    const float* __restrict__ x, const float* __restrict__ e,
    const float* __restrict__ idxf, float* __restrict__ out,
    float* __restrict__ diffp) {
  const size_t stride = (size_t)gridDim.x * 256;
  float local = 0.f;
  for (size_t f = (size_t)blockIdx.x * 256 + threadIdx.x; f < XELEMS; f += stride) {
    int n  = (int)(f >> 9);
    int rh = (int)(f & 511);
    int h  = rh >> 7;
    int d  = rh & 127;
    int k  = (int)idxf[n * HEADS + h];
    float q  = e[(size_t)(h * HD_ + d) * KC + k];
    float xv = x[f];
    out[f] = q;
    local += fabsf(xv - q);
  }
  for (int o = 32; o > 0; o >>= 1) local += __shfl_down(local, o, 64);
  __shared__ float ws[4];
  int lane = threadIdx.x & 63, wv = threadIdx.x >> 6;
  if (lane == 0) ws[wv] = local;
  __syncthreads();
  if (threadIdx.x == 0) {
    float s = (ws[0] + ws[1] + ws[2] + ws[3]) * (1.0f / 8388608.0f);
    atomicAdd(diffp, s);
  }
}

// ---------------------------------------------------------------------------
extern "C" void kernel_launch(void* const* d_in, const int* in_sizes, int n_in,
                              void* d_out, int out_size, void* d_ws, size_t ws_size,
                              hipStream_t stream) {
  const float* x = (const float*)d_in[0];
  const float* e = (const float*)d_in[1];
  float* out   = (float*)d_out;
  float*  ee32 = out + EE32_OFF;
  double* ee64 = (double*)(out + EE64_OFF);
  int*    cnt  = (int*)(out + CNT_OFF);
  int*    cand = (int*)(out + CAND_OFF);
  u16*    ebh  = (u16*)(out + EBH_OFF);
  u16*    ebl  = (u16*)(out + EBL_OFF);
  float* diffp = out + DIFFOFF;
  float* idxp  = out + IDXOFF;

  hipMemsetAsync(diffp, 0, sizeof(float), stream);
  hipMemsetAsync(cnt, 0, sizeof(int), stream);
  vq_prepass<<<dim3(KC / 64, HEADS), 256, 0, stream>>>(e, ee32, ee64, ebh, ebl);
  vq_mfma_kernel<<<dim3(N_TOK / 128, HEADS), 512, 0, stream>>>(x, ebh, ebl, ee32, idxp, cnt, cand);
  vq_rescue_kernel<<<1024, 256, 0, stream>>>(x, e, ee64, cand, cnt, idxp);
  vq_gather_kernel<<<2048, 256, 0, stream>>>(x, e, idxp, out, diffp);
}